// Round 1
// 3671.764 us; speedup vs baseline: 1.5132x; 1.5132x over previous
//
#include <hip/hip_runtime.h>
#include <stdint.h>

#define NB    64
#define LSEQ  2048
#define IND   128
#define HID   256
#define ACTD  18
#define G3    768            // 3*HID
#define MROWS (NB*LSEQ)      // 131072

typedef _Float16 half_t;
typedef half_t half2_t __attribute__((ext_vector_type(2)));

// ---------------- dtype helpers (manual bf16) ------------
__device__ __forceinline__ float bf2f(unsigned short u) { return __uint_as_float(((unsigned)u) << 16); }
__device__ __forceinline__ unsigned short f2bf(float f) {
  unsigned u = __float_as_uint(f);
  return (unsigned short)((u + 0x7FFFu + ((u >> 16) & 1u)) >> 16);
}
template<typename T> __device__ __forceinline__ float ldv(const T* p);
template<> __device__ __forceinline__ float ldv<float>(const float* p) { return *p; }
template<> __device__ __forceinline__ float ldv<unsigned short>(const unsigned short* p) { return bf2f(*p); }
template<typename T> __device__ __forceinline__ void stv(T* p, float v);
template<> __device__ __forceinline__ void stv<float>(float* p, float v) { *p = v; }
template<> __device__ __forceinline__ void stv<unsigned short>(unsigned short* p, float v) { *p = f2bf(v); }
template<typename T> __device__ __forceinline__ float4 ld4(const T* p);
template<> __device__ __forceinline__ float4 ld4<float>(const float* p) { return *(const float4*)p; }
template<> __device__ __forceinline__ float4 ld4<unsigned short>(const unsigned short* p) {
  ushort4 u = *(const ushort4*)p;
  float4 r; r.x = bf2f(u.x); r.y = bf2f(u.y); r.z = bf2f(u.z); r.w = bf2f(u.w); return r;
}

__device__ __forceinline__ float fdot2f(half2_t a, half2_t b, float c) {
#if __has_builtin(__builtin_amdgcn_fdot2)
  return __builtin_amdgcn_fdot2(a, b, c, false);
#else
  return fmaf((float)a.x, (float)b.x, fmaf((float)a.y, (float)b.y, c));
#endif
}

__device__ __forceinline__ float sigmoid_f(float x) { return __builtin_amdgcn_rcpf(1.f + __expf(-x)); }
__device__ __forceinline__ float tanh_f(float x) {
  const float t = __expf(-2.f * fabsf(x));
  const float r = (1.f - t) * __builtin_amdgcn_rcpf(1.f + t);
  return x < 0.f ? -r : r;
}

// butterfly add over lane bits 0/1 via DPP quad_perm (pure VALU, no LDS pipe)
template<int CTRL>
__device__ __forceinline__ float dpp_xor_add(float v) {
  const int r = __builtin_amdgcn_update_dpp(0, __float_as_int(v), CTRL, 0xF, 0xF, true);
  return v + __int_as_float(r);
}
#define DPP_XOR1 0xB1   // quad_perm(1,0,3,2)
#define DPP_XOR2 0x4E   // quad_perm(2,3,0,1)

// ---------------- generic fp32-accumulate GEMM: C[M,N] = op(A[M,K]) * W[N,K]^T + b --
// tile 64 x 128, K-chunks of 32, micro 4x8 per thread, 256 threads
template<typename IT, typename OT, bool RELU_IN, bool RELU_OUT, int K>
__global__ __launch_bounds__(256) void rnnq_gemm(const IT* __restrict__ A, const float* __restrict__ W,
                                                 const float* __restrict__ bias, OT* __restrict__ C,
                                                 int N) {
  __shared__ float At[32][68];
  __shared__ float Wt[32][136];
  const int t  = threadIdx.x;
  const long m0 = (long)blockIdx.x * 64;
  const int n0 = blockIdx.y * 128;
  const int ty = t >> 4, tx = t & 15;
  const int sr = t >> 2, skq = (t & 3) * 4;
  const int wc = t >> 1, wkh = (t & 1) * 16;
  float acc[4][8] = {{0.f}};
  for (int kc = 0; kc < K; kc += 32) {
    float4 a0 = ld4(A + (m0 + sr) * (size_t)K + kc + skq);
    float4 a1 = ld4(A + (m0 + sr) * (size_t)K + kc + skq + 16);
    if (RELU_IN) {
      a0.x = fmaxf(a0.x, 0.f); a0.y = fmaxf(a0.y, 0.f); a0.z = fmaxf(a0.z, 0.f); a0.w = fmaxf(a0.w, 0.f);
      a1.x = fmaxf(a1.x, 0.f); a1.y = fmaxf(a1.y, 0.f); a1.z = fmaxf(a1.z, 0.f); a1.w = fmaxf(a1.w, 0.f);
    }
    const float* wp = W + (size_t)(n0 + wc) * K + kc + wkh;
    float4 w0 = *(const float4*)(wp + 0);
    float4 w1 = *(const float4*)(wp + 4);
    float4 w2 = *(const float4*)(wp + 8);
    float4 w3 = *(const float4*)(wp + 12);
    At[skq+0][sr] = a0.x; At[skq+1][sr] = a0.y; At[skq+2][sr] = a0.z; At[skq+3][sr] = a0.w;
    At[skq+16][sr] = a1.x; At[skq+17][sr] = a1.y; At[skq+18][sr] = a1.z; At[skq+19][sr] = a1.w;
    Wt[wkh+0][wc] = w0.x; Wt[wkh+1][wc] = w0.y; Wt[wkh+2][wc] = w0.z; Wt[wkh+3][wc] = w0.w;
    Wt[wkh+4][wc] = w1.x; Wt[wkh+5][wc] = w1.y; Wt[wkh+6][wc] = w1.z; Wt[wkh+7][wc] = w1.w;
    Wt[wkh+8][wc] = w2.x; Wt[wkh+9][wc] = w2.y; Wt[wkh+10][wc] = w2.z; Wt[wkh+11][wc] = w2.w;
    Wt[wkh+12][wc] = w3.x; Wt[wkh+13][wc] = w3.y; Wt[wkh+14][wc] = w3.z; Wt[wkh+15][wc] = w3.w;
    __syncthreads();
    #pragma unroll
    for (int k = 0; k < 32; ++k) {
      const float4 av  = *(const float4*)&At[k][ty*4];
      const float4 bv0 = *(const float4*)&Wt[k][tx*8];
      const float4 bv1 = *(const float4*)&Wt[k][tx*8+4];
      const float am[4] = {av.x, av.y, av.z, av.w};
      const float bm[8] = {bv0.x, bv0.y, bv0.z, bv0.w, bv1.x, bv1.y, bv1.z, bv1.w};
      #pragma unroll
      for (int i = 0; i < 4; ++i)
        #pragma unroll
        for (int jj = 0; jj < 8; ++jj)
          acc[i][jj] = fmaf(am[i], bm[jj], acc[i][jj]);
    }
    __syncthreads();
  }
  #pragma unroll
  for (int i = 0; i < 4; ++i) {
    const long r = m0 + ty*4 + i;
    OT* cp = C + r * (size_t)N + n0 + tx*8;
    #pragma unroll
    for (int jj = 0; jj < 8; ++jj) {
      float v = acc[i][jj] + bias[n0 + tx*8 + jj];
      if (RELU_OUT) v = fmaxf(v, 0.f);
      stv(cp + jj, v);
    }
  }
}

// ---------------- fc2: Q[131072,18] = X[131072,256] * W2[18,256]^T + b2 -------------
template<typename YT>
__global__ __launch_bounds__(256) void rnnq_fc2(const YT* __restrict__ X, const float* __restrict__ W2,
                                                const float* __restrict__ b2, float* __restrict__ Q) {
  __shared__ float xs[32][260];
  __shared__ float ws2[ACTD][260];
  const int t = threadIdx.x;
  const long r0 = (long)blockIdx.x * 32;
  for (int i = t; i < 32*64; i += 256) {
    const int r = i >> 6, c4 = (i & 63) * 4;
    const float4 v = ld4(X + (r0 + r) * (size_t)HID + c4);
    *(float4*)&xs[r][c4] = v;
  }
  for (int i = t; i < ACTD*64; i += 256) {
    const int a = i >> 6, c4 = (i & 63) * 4;
    *(float4*)&ws2[a][c4] = *(const float4*)(W2 + a*HID + c4);
  }
  __syncthreads();
  for (int idx = t; idx < 32*ACTD; idx += 256) {
    const int r = idx / ACTD, a = idx - r*ACTD;
    float s0 = 0.f, s1 = 0.f;
    #pragma unroll
    for (int k4 = 0; k4 < HID/4; k4 += 2) {
      const float4 xv = *(const float4*)&xs[r][k4*4];
      const float4 wv = *(const float4*)&ws2[a][k4*4];
      s0 = fmaf(xv.x, wv.x, s0); s0 = fmaf(xv.y, wv.y, s0);
      s0 = fmaf(xv.z, wv.z, s0); s0 = fmaf(xv.w, wv.w, s0);
      const float4 xv2 = *(const float4*)&xs[r][k4*4+4];
      const float4 wv2 = *(const float4*)&ws2[a][k4*4+4];
      s1 = fmaf(xv2.x, wv2.x, s1); s1 = fmaf(xv2.y, wv2.y, s1);
      s1 = fmaf(xv2.z, wv2.z, s1); s1 = fmaf(xv2.w, wv2.w, s1);
    }
    Q[(r0 + r) * ACTD + a] = s0 + s1 + b2[a];
  }
}

// ---------------- the scan, v2: one block per row (64 main + 64 virtual) ------------
// 1024 threads: thread = (j = t>>2 owns h-column j for all 3 gates, kq = t&3 owns 64 k).
// W slice = 96 half2 regs/thread (fits 128 VGPR, no AGPR round-trips). 16 waves/CU.
// Reduce over kq = 2 DPP quad_perm stages (pure VALU). Epilogue on ALL lanes (1 j each).
// gi prefetch + gru_out store issued at step TOP so the __syncthreads vmcnt(0) drain is
// covered by the dot2 work. h kept f16 in LDS, permuted layout -> conflict-free b128 reads.
template<typename GIT>
__global__ __launch_bounds__(1024, 4) void rnnq_scan2(
    const GIT* __restrict__ gi, const int* __restrict__ dones,
    const float* __restrict__ w_hh, const float* __restrict__ b_hh, const float* __restrict__ b_ih,
    const float* __restrict__ h0, float* __restrict__ gru_out, float* __restrict__ next_hx) {
  const int row = blockIdx.x;       // 0..127
  const int n = row & 63;
  const bool is_main = row < 64;
  const int t = threadIdx.x;
  const int j = t >> 2;             // 0..255: this thread's h column
  const int kq = t & 3;             // 0..3: k-span of 64

  __shared__ __align__(16) half2_t hb[2][128];  // permuted h, double buffered (512 B each)
  __shared__ float sbhh[G3];
  __shared__ int cred[16];

  // ---- c = last done index for this n ----
  int cmax = 0;
  for (int i = t; i < LSEQ; i += 1024) if (dones[n*LSEQ + i]) cmax = i;
  #pragma unroll
  for (int m = 1; m < 64; m <<= 1) { int o = __shfl_xor(cmax, m, 64); cmax = cmax > o ? cmax : o; }
  if ((t & 63) == 0) cred[t >> 6] = cmax;
  for (int i = t; i < G3; i += 1024) sbhh[i] = b_hh[i];
  __syncthreads();
  int c = cred[0];
  #pragma unroll
  for (int w = 1; w < 16; ++w) c = c > cred[w] ? c : cred[w];
  const int off = is_main ? 0 : c;

  // ---- pack this thread's w_hh slice: rows {j, 256+j, 512+j}, cols kq*64..+63 -> f16 ----
  half2_t wr[32], wz[32], wn[32];
  {
    const size_t cb = (size_t)kq * 64;
    const float* pr = w_hh + (size_t)j * HID + cb;
    const float* pz = w_hh + (size_t)(HID + j) * HID + cb;
    const float* pn = w_hh + (size_t)(2*HID + j) * HID + cb;
    #pragma unroll
    for (int q = 0; q < 16; ++q) {
      const float4 vr = *(const float4*)(pr + q*4);
      const float4 vz = *(const float4*)(pz + q*4);
      const float4 vnn = *(const float4*)(pn + q*4);
      wr[q*2].x = (half_t)vr.x;  wr[q*2].y = (half_t)vr.y;  wr[q*2+1].x = (half_t)vr.z;  wr[q*2+1].y = (half_t)vr.w;
      wz[q*2].x = (half_t)vz.x;  wz[q*2].y = (half_t)vz.y;  wz[q*2+1].x = (half_t)vz.z;  wz[q*2+1].y = (half_t)vz.w;
      wn[q*2].x = (half_t)vnn.x; wn[q*2].y = (half_t)vnn.y; wn[q*2+1].x = (half_t)vnn.z; wn[q*2+1].y = (half_t)vnn.w;
    }
  }

  // ---- LDS addressing ----
  // permutation: original half2 chunk c=(kq*32+u*4+r) stored at slot u*16+kq*4+r.
  // reader (lane kq, chunk u): slots u*16+kq*4..+3 -> byte u*64 + kq*16 (64B contiguous per 4 kq, conflict-free)
  const int rdoff = kq * 16;                       // byte offset into buffer
  const int cslot = j >> 1;
  const int wslot = ((cslot >> 2) & 7) * 16 + (cslot >> 5) * 4 + (cslot & 3);
  const int wroff = wslot * 4 + (j & 1) * 2;       // byte offset of element j
  char* hbase = (char*)&hb[0][0];

  // ---- initial state ----
  float hprev = h0[n*HID + j];
  if (kq == 0) *(half_t*)(hbase + wroff) = (half_t)hprev;   // fill hb[0]
  const GIT* gp = gi + ((size_t)n * LSEQ + off) * (size_t)G3 + j;
  float g_r = ldv(gp); float g_z = ldv(gp + HID); float g_n = ldv(gp + 2*HID);
  gp += G3;
  int dcur = dones[n*LSEQ + off];
  float* goutp = gru_out + (size_t)n * LSEQ * HID + j;
  __syncthreads();

  #pragma unroll 1
  for (int step = 0; step < LSEQ; ++step) {
    const int buf = step & 1;
    // ---- early-issue: deferred store of step-1 output + prefetch of step+1 inputs ----
    if (step > 0) {
      if (kq == 0 && is_main) *goutp = hprev;
      goutp += HID;
    }
    const int idxn = off + step + 1;
    float ng_r = g_r, ng_z = g_z, ng_n = g_n;
    int dnext = 0;
    if (idxn < LSEQ) {
      dnext = dones[n*LSEQ + idxn];
      ng_r = ldv(gp); ng_z = ldv(gp + HID); ng_n = ldv(gp + 2*HID);
      gp += G3;
    } else if (idxn == LSEQ) {
      ng_r = b_ih[j]; ng_z = b_ih[HID + j]; ng_n = b_ih[2*HID + j];
    }

    // ---- matvec partials over this lane's 64 k ----
    const char* hp = (const char*)&hb[buf][0] + rdoff;
    float a0 = 0.f, a1 = 0.f, a2 = 0.f;
    #pragma unroll
    for (int u = 0; u < 8; ++u) {
      half2_t hv[4];
      *(float4*)hv = *(const float4*)(hp + u*64);
      #pragma unroll
      for (int r = 0; r < 4; ++r) {
        a0 = fdot2f(wr[u*4+r], hv[r], a0);
        a1 = fdot2f(wz[u*4+r], hv[r], a1);
        a2 = fdot2f(wn[u*4+r], hv[r], a2);
      }
    }
    // ---- reduce over kq (lane bits 0..1), results land in all lanes ----
    a0 = dpp_xor_add<DPP_XOR1>(a0); a0 = dpp_xor_add<DPP_XOR2>(a0);
    a1 = dpp_xor_add<DPP_XOR1>(a1); a1 = dpp_xor_add<DPP_XOR2>(a1);
    a2 = dpp_xor_add<DPP_XOR1>(a2); a2 = dpp_xor_add<DPP_XOR2>(a2);

    // ---- epilogue: every lane computes its single j (kq lanes are duplicates) ----
    const float m = dcur ? 0.f : 1.f;
    const float rr = sigmoid_f(g_r + fmaf(m, a0, sbhh[j]));
    const float zz = sigmoid_f(g_z + fmaf(m, a1, sbhh[HID + j]));
    const float nnv = tanh_f(g_n + rr * fmaf(m, a2, sbhh[2*HID + j]));
    const float hnew = fmaf(1.f - zz, nnv, zz * (m * hprev));
    hprev = hnew;

    // ---- publish h for next step (other buffer) ----
    if (kq == 0) *(half_t*)(hbase + ((buf ^ 1) * 512) + wroff) = (half_t)hnew;
    g_r = ng_r; g_z = ng_z; g_n = ng_n; dcur = dnext;
    __syncthreads();
  }

  if (kq == 0) {
    if (is_main) *goutp = hprev;                       // step 2047 output
    else *(next_hx + n*HID + j) = hprev;
  }
}

// ---------------- host-side pipeline ----------------
template<typename GIT, typename YT>
static void run_pipeline(const float* state, const float* h0, const int* dones,
                         const float* w_ih, const float* w_hh, const float* b_ih, const float* b_hh,
                         const float* fc0_w, const float* fc0_b, const float* fc1_w, const float* fc1_b,
                         const float* fc2_w, const float* fc2_b,
                         float* q_out, float* gru_out, float* hx_out,
                         char* ws, size_t y1_off, hipStream_t stream) {
  GIT* gi = (GIT*)ws;
  YT* y0 = (YT*)ws;                       // aliases gi (gi dead after scan)
  YT* y1 = (YT*)(ws + y1_off);

  rnnq_gemm<float, GIT, false, false, IND><<<dim3(MROWS/64, G3/128), 256, 0, stream>>>(
      state, w_ih, b_ih, gi, G3);
  rnnq_scan2<GIT><<<128, 1024, 0, stream>>>(gi, dones, w_hh, b_hh, b_ih, h0, gru_out, hx_out);
  rnnq_gemm<float, YT, true, true, HID><<<dim3(MROWS/64, HID/128), 256, 0, stream>>>(
      gru_out, fc0_w, fc0_b, y0, HID);
  rnnq_gemm<YT, YT, false, true, HID><<<dim3(MROWS/64, HID/128), 256, 0, stream>>>(
      y0, fc1_w, fc1_b, y1, HID);
  rnnq_fc2<YT><<<MROWS/32, 256, 0, stream>>>(y1, fc2_w, fc2_b, q_out);
}

extern "C" void kernel_launch(void* const* d_in, const int* in_sizes, int n_in,
                              void* d_out, int out_size, void* d_ws, size_t ws_size,
                              hipStream_t stream) {
  const float* state = (const float*)d_in[0];
  const float* h0    = (const float*)d_in[1];
  const int*   dones = (const int*)d_in[2];
  const float* w_ih  = (const float*)d_in[3];
  const float* w_hh  = (const float*)d_in[4];
  const float* b_ih  = (const float*)d_in[5];
  const float* b_hh  = (const float*)d_in[6];
  const float* fc0_w = (const float*)d_in[7];
  const float* fc0_b = (const float*)d_in[8];
  const float* fc1_w = (const float*)d_in[9];
  const float* fc1_b = (const float*)d_in[10];
  const float* fc2_w = (const float*)d_in[11];
  const float* fc2_b = (const float*)d_in[12];

  float* q_out   = (float*)d_out;                       // [64,2048,18]
  float* gru_out = q_out + (size_t)MROWS * ACTD;        // [64,2048,256]
  float* hx_out  = gru_out + (size_t)MROWS * HID;       // [1,64,256]
  char* ws = (char*)d_ws;

  const size_t GI_F32  = (size_t)MROWS * G3 * 4;        // 402,653,184
  const size_t Y_F32   = (size_t)MROWS * HID * 4;       // 134,217,728
  const size_t Y_BF16  = (size_t)MROWS * HID * 2;       //  67,108,864

  if (ws_size >= GI_F32) {
    run_pipeline<float, float>(state, h0, dones, w_ih, w_hh, b_ih, b_hh,
                               fc0_w, fc0_b, fc1_w, fc1_b, fc2_w, fc2_b,
                               q_out, gru_out, hx_out, ws, Y_F32, stream);
  } else if (ws_size >= 2 * Y_F32) {
    run_pipeline<unsigned short, float>(state, h0, dones, w_ih, w_hh, b_ih, b_hh,
                                        fc0_w, fc0_b, fc1_w, fc1_b, fc2_w, fc2_b,
                                        q_out, gru_out, hx_out, ws, Y_F32, stream);
  } else {
    run_pipeline<unsigned short, unsigned short>(state, h0, dones, w_ih, w_hh, b_ih, b_hh,
                                                 fc0_w, fc0_b, fc1_w, fc1_b, fc2_w, fc2_b,
                                                 q_out, gru_out, hx_out, ws, Y_BF16, stream);
  }
}

// Round 2
// 3344.624 us; speedup vs baseline: 1.6612x; 1.0978x over previous
//
#include <hip/hip_runtime.h>
#include <stdint.h>

#define NB    64
#define LSEQ  2048
#define IND   128
#define HID   256
#define ACTD  18
#define G3    768            // 3*HID
#define MROWS (NB*LSEQ)      // 131072

typedef _Float16 half_t;
typedef half_t half2_t __attribute__((ext_vector_type(2)));

// ---------------- dtype helpers (manual bf16) ------------
__device__ __forceinline__ float bf2f(unsigned short u) { return __uint_as_float(((unsigned)u) << 16); }
__device__ __forceinline__ unsigned short f2bf(float f) {
  unsigned u = __float_as_uint(f);
  return (unsigned short)((u + 0x7FFFu + ((u >> 16) & 1u)) >> 16);
}
template<typename T> __device__ __forceinline__ float ldv(const T* p);
template<> __device__ __forceinline__ float ldv<float>(const float* p) { return *p; }
template<> __device__ __forceinline__ float ldv<unsigned short>(const unsigned short* p) { return bf2f(*p); }
template<typename T> __device__ __forceinline__ void stv(T* p, float v);
template<> __device__ __forceinline__ void stv<float>(float* p, float v) { *p = v; }
template<> __device__ __forceinline__ void stv<unsigned short>(unsigned short* p, float v) { *p = f2bf(v); }
template<typename T> __device__ __forceinline__ float4 ld4(const T* p);
template<> __device__ __forceinline__ float4 ld4<float>(const float* p) { return *(const float4*)p; }
template<> __device__ __forceinline__ float4 ld4<unsigned short>(const unsigned short* p) {
  ushort4 u = *(const ushort4*)p;
  float4 r; r.x = bf2f(u.x); r.y = bf2f(u.y); r.z = bf2f(u.z); r.w = bf2f(u.w); return r;
}

__device__ __forceinline__ float fdot2f(half2_t a, half2_t b, float c) {
#if __has_builtin(__builtin_amdgcn_fdot2)
  return __builtin_amdgcn_fdot2(a, b, c, false);
#else
  return fmaf((float)a.x, (float)b.x, fmaf((float)a.y, (float)b.y, c));
#endif
}

__device__ __forceinline__ float sigmoid_f(float x) { return __builtin_amdgcn_rcpf(1.f + __expf(-x)); }
__device__ __forceinline__ float tanh_f(float x) {
  const float t = __expf(-2.f * fabsf(x));
  const float r = (1.f - t) * __builtin_amdgcn_rcpf(1.f + t);
  return x < 0.f ? -r : r;
}

// butterfly add over lane bit 0 via DPP quad_perm (pure VALU, no LDS pipe)
__device__ __forceinline__ float dpp_xor1_add(float v) {
  const int r = __builtin_amdgcn_update_dpp(0, __float_as_int(v), 0xB1 /*quad_perm(1,0,3,2)*/, 0xF, 0xF, true);
  return v + __int_as_float(r);
}

// ---------------- generic fp32-accumulate GEMM: C[M,N] = op(A[M,K]) * W[N,K]^T + b --
// tile 64 x 128, K-chunks of 32, micro 4x8 per thread, 256 threads
template<typename IT, typename OT, bool RELU_IN, bool RELU_OUT, int K>
__global__ __launch_bounds__(256) void rnnq_gemm(const IT* __restrict__ A, const float* __restrict__ W,
                                                 const float* __restrict__ bias, OT* __restrict__ C,
                                                 int N) {
  __shared__ float At[32][68];
  __shared__ float Wt[32][136];
  const int t  = threadIdx.x;
  const long m0 = (long)blockIdx.x * 64;
  const int n0 = blockIdx.y * 128;
  const int ty = t >> 4, tx = t & 15;
  const int sr = t >> 2, skq = (t & 3) * 4;
  const int wc = t >> 1, wkh = (t & 1) * 16;
  float acc[4][8] = {{0.f}};
  for (int kc = 0; kc < K; kc += 32) {
    float4 a0 = ld4(A + (m0 + sr) * (size_t)K + kc + skq);
    float4 a1 = ld4(A + (m0 + sr) * (size_t)K + kc + skq + 16);
    if (RELU_IN) {
      a0.x = fmaxf(a0.x, 0.f); a0.y = fmaxf(a0.y, 0.f); a0.z = fmaxf(a0.z, 0.f); a0.w = fmaxf(a0.w, 0.f);
      a1.x = fmaxf(a1.x, 0.f); a1.y = fmaxf(a1.y, 0.f); a1.z = fmaxf(a1.z, 0.f); a1.w = fmaxf(a1.w, 0.f);
    }
    const float* wp = W + (size_t)(n0 + wc) * K + kc + wkh;
    float4 w0 = *(const float4*)(wp + 0);
    float4 w1 = *(const float4*)(wp + 4);
    float4 w2 = *(const float4*)(wp + 8);
    float4 w3 = *(const float4*)(wp + 12);
    At[skq+0][sr] = a0.x; At[skq+1][sr] = a0.y; At[skq+2][sr] = a0.z; At[skq+3][sr] = a0.w;
    At[skq+16][sr] = a1.x; At[skq+17][sr] = a1.y; At[skq+18][sr] = a1.z; At[skq+19][sr] = a1.w;
    Wt[wkh+0][wc] = w0.x; Wt[wkh+1][wc] = w0.y; Wt[wkh+2][wc] = w0.z; Wt[wkh+3][wc] = w0.w;
    Wt[wkh+4][wc] = w1.x; Wt[wkh+5][wc] = w1.y; Wt[wkh+6][wc] = w1.z; Wt[wkh+7][wc] = w1.w;
    Wt[wkh+8][wc] = w2.x; Wt[wkh+9][wc] = w2.y; Wt[wkh+10][wc] = w2.z; Wt[wkh+11][wc] = w2.w;
    Wt[wkh+12][wc] = w3.x; Wt[wkh+13][wc] = w3.y; Wt[wkh+14][wc] = w3.z; Wt[wkh+15][wc] = w3.w;
    __syncthreads();
    #pragma unroll
    for (int k = 0; k < 32; ++k) {
      const float4 av  = *(const float4*)&At[k][ty*4];
      const float4 bv0 = *(const float4*)&Wt[k][tx*8];
      const float4 bv1 = *(const float4*)&Wt[k][tx*8+4];
      const float am[4] = {av.x, av.y, av.z, av.w};
      const float bm[8] = {bv0.x, bv0.y, bv0.z, bv0.w, bv1.x, bv1.y, bv1.z, bv1.w};
      #pragma unroll
      for (int i = 0; i < 4; ++i)
        #pragma unroll
        for (int jj = 0; jj < 8; ++jj)
          acc[i][jj] = fmaf(am[i], bm[jj], acc[i][jj]);
    }
    __syncthreads();
  }
  #pragma unroll
  for (int i = 0; i < 4; ++i) {
    const long r = m0 + ty*4 + i;
    OT* cp = C + r * (size_t)N + n0 + tx*8;
    #pragma unroll
    for (int jj = 0; jj < 8; ++jj) {
      float v = acc[i][jj] + bias[n0 + tx*8 + jj];
      if (RELU_OUT) v = fmaxf(v, 0.f);
      stv(cp + jj, v);
    }
  }
}

// ---------------- fc2: Q[131072,18] = X[131072,256] * W2[18,256]^T + b2 -------------
template<typename YT>
__global__ __launch_bounds__(256) void rnnq_fc2(const YT* __restrict__ X, const float* __restrict__ W2,
                                                const float* __restrict__ b2, float* __restrict__ Q) {
  __shared__ float xs[32][260];
  __shared__ float ws2[ACTD][260];
  const int t = threadIdx.x;
  const long r0 = (long)blockIdx.x * 32;
  for (int i = t; i < 32*64; i += 256) {
    const int r = i >> 6, c4 = (i & 63) * 4;
    const float4 v = ld4(X + (r0 + r) * (size_t)HID + c4);
    *(float4*)&xs[r][c4] = v;
  }
  for (int i = t; i < ACTD*64; i += 256) {
    const int a = i >> 6, c4 = (i & 63) * 4;
    *(float4*)&ws2[a][c4] = *(const float4*)(W2 + a*HID + c4);
  }
  __syncthreads();
  for (int idx = t; idx < 32*ACTD; idx += 256) {
    const int r = idx / ACTD, a = idx - r*ACTD;
    float s0 = 0.f, s1 = 0.f;
    #pragma unroll
    for (int k4 = 0; k4 < HID/4; k4 += 2) {
      const float4 xv = *(const float4*)&xs[r][k4*4];
      const float4 wv = *(const float4*)&ws2[a][k4*4];
      s0 = fmaf(xv.x, wv.x, s0); s0 = fmaf(xv.y, wv.y, s0);
      s0 = fmaf(xv.z, wv.z, s0); s0 = fmaf(xv.w, wv.w, s0);
      const float4 xv2 = *(const float4*)&xs[r][k4*4+4];
      const float4 wv2 = *(const float4*)&ws2[a][k4*4+4];
      s1 = fmaf(xv2.x, wv2.x, s1); s1 = fmaf(xv2.y, wv2.y, s1);
      s1 = fmaf(xv2.z, wv2.z, s1); s1 = fmaf(xv2.w, wv2.w, s1);
    }
    Q[(r0 + r) * ACTD + a] = s0 + s1 + b2[a];
  }
}

// ---------------- the scan, v3: one block per row (64 main + 64 virtual) ------------
// 512 threads: thread = (j = t>>1 owns h-column j for all 3 gates, kq = t&1 owns 128 k).
// W slice = 192 half2 = 192 arch VGPRs/thread (launch_bounds(512,2) -> 256-reg budget,
// no AGPR round-trips). Reduce over kq = one DPP quad_perm stage. Epilogue on all lanes.
// Barrier = lgkmcnt-only (no vmcnt drain): gi prefetch completes at the register copy
// AFTER the barrier (full-step slack); gru_out stores never block. dones as LDS bitmask;
// b_hh/b_ih held in registers. h f16 in LDS, linear layout (reads broadcast: 2 distinct
// addresses/wave -> conflict-free).
template<typename GIT>
__global__ __launch_bounds__(512, 2) void rnnq_scan3(
    const GIT* __restrict__ gi, const int* __restrict__ dones,
    const float* __restrict__ w_hh, const float* __restrict__ b_hh, const float* __restrict__ b_ih,
    const float* __restrict__ h0, float* __restrict__ gru_out, float* __restrict__ next_hx) {
  const int row = blockIdx.x;       // 0..127
  const int n = row & 63;
  const bool is_main = row < 64;
  const int t = threadIdx.x;
  const int j = t >> 1;             // 0..255: this thread's h column
  const int kq = t & 1;             // 0..1: k-span of 128

  __shared__ __align__(16) half2_t hb[2][128];     // h (f16), double buffered, 512 B each
  __shared__ unsigned long long dmask[LSEQ/64];    // dones bitmask (256 B)
  __shared__ int cred[8];

  // ---- dones bitmask + c = last done index for this n ----
  int cmax = 0;
  #pragma unroll
  for (int c4 = 0; c4 < LSEQ/512; ++c4) {
    const int i = c4*512 + t;
    const int d = dones[n*LSEQ + i];
    if (d) cmax = i;
    const unsigned long long mb = __ballot(d != 0);
    if ((t & 63) == 0) dmask[i >> 6] = mb;
  }
  #pragma unroll
  for (int m = 1; m < 64; m <<= 1) { int o = __shfl_xor(cmax, m, 64); cmax = cmax > o ? cmax : o; }
  if ((t & 63) == 0) cred[t >> 6] = cmax;
  __syncthreads();
  int c = cred[0];
  #pragma unroll
  for (int w = 1; w < 8; ++w) c = c > cred[w] ? c : cred[w];
  const int off = is_main ? 0 : c;

  // ---- pack this thread's w_hh slice: rows {j, 256+j, 512+j}, cols kq*128..+127 -> f16 ----
  half2_t wr[64], wz[64], wn[64];
  {
    const size_t cb = (size_t)kq * 128;
    const float* pr = w_hh + (size_t)j * HID + cb;
    const float* pz = w_hh + (size_t)(HID + j) * HID + cb;
    const float* pn = w_hh + (size_t)(2*HID + j) * HID + cb;
    #pragma unroll
    for (int q = 0; q < 32; ++q) {
      const float4 vr = *(const float4*)(pr + q*4);
      const float4 vz = *(const float4*)(pz + q*4);
      const float4 vnn = *(const float4*)(pn + q*4);
      wr[q*2].x = (half_t)vr.x;  wr[q*2].y = (half_t)vr.y;  wr[q*2+1].x = (half_t)vr.z;  wr[q*2+1].y = (half_t)vr.w;
      wz[q*2].x = (half_t)vz.x;  wz[q*2].y = (half_t)vz.y;  wz[q*2+1].x = (half_t)vz.z;  wz[q*2+1].y = (half_t)vz.w;
      wn[q*2].x = (half_t)vnn.x; wn[q*2].y = (half_t)vnn.y; wn[q*2+1].x = (half_t)vnn.z; wn[q*2+1].y = (half_t)vnn.w;
    }
  }

  // ---- per-thread constants in registers ----
  const float bhr = b_hh[j], bhz = b_hh[HID + j], bhn = b_hh[2*HID + j];
  const float bir = b_ih[j], biz = b_ih[HID + j], bin_ = b_ih[2*HID + j];

  char* hbase = (char*)&hb[0][0];
  const char* hrd = hbase + kq * 256;   // this lane's k-span within a buffer

  // ---- initial state ----
  float hprev = h0[n*HID + j];
  if (kq == 0) *(half_t*)(hbase + j*2) = (half_t)hprev;   // fill hb[0]
  const GIT* gp = gi + ((size_t)n * LSEQ + off) * (size_t)G3 + j;
  float g_r = ldv(gp); float g_z = ldv(gp + HID); float g_n = ldv(gp + 2*HID);
  gp += G3;
  float* goutp = gru_out + (size_t)n * LSEQ * HID + j;
  __syncthreads();
  int dcur = (int)((dmask[off >> 6] >> (off & 63)) & 1ull);

  #pragma unroll 1
  for (int step = 0; step < LSEQ; ++step) {
    const int buf = step & 1;
    // ---- prefetch step+1 inputs (consumed after the barrier below) ----
    const int idxn = off + step + 1;
    float ng_r, ng_z, ng_n;
    int dnext = 0;
    if (idxn < LSEQ) {
      ng_r = ldv(gp); ng_z = ldv(gp + HID); ng_n = ldv(gp + 2*HID);
      gp += G3;
      dnext = (int)((dmask[idxn >> 6] >> (idxn & 63)) & 1ull);
    } else {
      ng_r = bir; ng_z = biz; ng_n = bin_;
    }

    // ---- matvec partials over this lane's 128 k (6 independent dot2 chains) ----
    const char* hp = hrd + buf * 512;
    float a0a = 0.f, a0b = 0.f, a1a = 0.f, a1b = 0.f, a2a = 0.f, a2b = 0.f;
    #pragma unroll
    for (int u = 0; u < 16; ++u) {
      half2_t hv[4];
      *(float4*)hv = *(const float4*)(hp + u*16);
      #pragma unroll
      for (int r = 0; r < 4; ++r) {
        const int w = u*4 + r;
        if (w & 1) { a0b = fdot2f(wr[w], hv[r], a0b); a1b = fdot2f(wz[w], hv[r], a1b); a2b = fdot2f(wn[w], hv[r], a2b); }
        else       { a0a = fdot2f(wr[w], hv[r], a0a); a1a = fdot2f(wz[w], hv[r], a1a); a2a = fdot2f(wn[w], hv[r], a2a); }
      }
    }
    float s0 = a0a + a0b, s1 = a1a + a1b, s2 = a2a + a2b;
    // ---- reduce over kq (lane bit 0), results land in both lanes ----
    s0 = dpp_xor1_add(s0);
    s1 = dpp_xor1_add(s1);
    s2 = dpp_xor1_add(s2);

    // ---- epilogue: every lane computes its single j (kq pair are duplicates) ----
    const float m = dcur ? 0.f : 1.f;
    const float rr = sigmoid_f(g_r + fmaf(m, s0, bhr));
    const float zz = sigmoid_f(g_z + fmaf(m, s1, bhz));
    const float nnv = tanh_f(g_n + rr * fmaf(m, s2, bhn));
    const float hnew = fmaf(1.f - zz, nnv, zz * (m * hprev));
    hprev = hnew;

    // ---- publish h for next step (other buffer) + output ----
    if (kq == 0) {
      *(half_t*)(hbase + (buf ^ 1) * 512 + j*2) = (half_t)hnew;
      if (is_main) *goutp = hnew;
    }
    goutp += HID;

    // ---- barrier WITHOUT vmcnt drain: only LDS must be visible ----
    asm volatile("s_waitcnt lgkmcnt(0)\n\ts_barrier" ::: "memory");

    // ---- consume prefetch (vmcnt wait lands here, a full step after issue) ----
    g_r = ng_r; g_z = ng_z; g_n = ng_n; dcur = dnext;
  }

  if (kq == 0 && !is_main) next_hx[n*HID + j] = hprev;
}

// ---------------- host-side pipeline ----------------
template<typename GIT, typename YT>
static void run_pipeline(const float* state, const float* h0, const int* dones,
                         const float* w_ih, const float* w_hh, const float* b_ih, const float* b_hh,
                         const float* fc0_w, const float* fc0_b, const float* fc1_w, const float* fc1_b,
                         const float* fc2_w, const float* fc2_b,
                         float* q_out, float* gru_out, float* hx_out,
                         char* ws, size_t y1_off, hipStream_t stream) {
  GIT* gi = (GIT*)ws;
  YT* y0 = (YT*)ws;                       // aliases gi (gi dead after scan)
  YT* y1 = (YT*)(ws + y1_off);

  rnnq_gemm<float, GIT, false, false, IND><<<dim3(MROWS/64, G3/128), 256, 0, stream>>>(
      state, w_ih, b_ih, gi, G3);
  rnnq_scan3<GIT><<<128, 512, 0, stream>>>(gi, dones, w_hh, b_hh, b_ih, h0, gru_out, hx_out);
  rnnq_gemm<float, YT, true, true, HID><<<dim3(MROWS/64, HID/128), 256, 0, stream>>>(
      gru_out, fc0_w, fc0_b, y0, HID);
  rnnq_gemm<YT, YT, false, true, HID><<<dim3(MROWS/64, HID/128), 256, 0, stream>>>(
      y0, fc1_w, fc1_b, y1, HID);
  rnnq_fc2<YT><<<MROWS/32, 256, 0, stream>>>(y1, fc2_w, fc2_b, q_out);
}

extern "C" void kernel_launch(void* const* d_in, const int* in_sizes, int n_in,
                              void* d_out, int out_size, void* d_ws, size_t ws_size,
                              hipStream_t stream) {
  const float* state = (const float*)d_in[0];
  const float* h0    = (const float*)d_in[1];
  const int*   dones = (const int*)d_in[2];
  const float* w_ih  = (const float*)d_in[3];
  const float* w_hh  = (const float*)d_in[4];
  const float* b_ih  = (const float*)d_in[5];
  const float* b_hh  = (const float*)d_in[6];
  const float* fc0_w = (const float*)d_in[7];
  const float* fc0_b = (const float*)d_in[8];
  const float* fc1_w = (const float*)d_in[9];
  const float* fc1_b = (const float*)d_in[10];
  const float* fc2_w = (const float*)d_in[11];
  const float* fc2_b = (const float*)d_in[12];

  float* q_out   = (float*)d_out;                       // [64,2048,18]
  float* gru_out = q_out + (size_t)MROWS * ACTD;        // [64,2048,256]
  float* hx_out  = gru_out + (size_t)MROWS * HID;       // [1,64,256]
  char* ws = (char*)d_ws;

  const size_t GI_F32  = (size_t)MROWS * G3 * 4;        // 402,653,184
  const size_t Y_F32   = (size_t)MROWS * HID * 4;       // 134,217,728
  const size_t Y_BF16  = (size_t)MROWS * HID * 2;       //  67,108,864

  if (ws_size >= GI_F32) {
    run_pipeline<float, float>(state, h0, dones, w_ih, w_hh, b_ih, b_hh,
                               fc0_w, fc0_b, fc1_w, fc1_b, fc2_w, fc2_b,
                               q_out, gru_out, hx_out, ws, Y_F32, stream);
  } else if (ws_size >= 2 * Y_F32) {
    run_pipeline<unsigned short, float>(state, h0, dones, w_ih, w_hh, b_ih, b_hh,
                                        fc0_w, fc0_b, fc1_w, fc1_b, fc2_w, fc2_b,
                                        q_out, gru_out, hx_out, ws, Y_F32, stream);
  } else {
    run_pipeline<unsigned short, unsigned short>(state, h0, dones, w_ih, w_hh, b_ih, b_hh,
                                                 fc0_w, fc0_b, fc1_w, fc1_b, fc2_w, fc2_b,
                                                 q_out, gru_out, hx_out, ws, Y_BF16, stream);
  }
}